// Round 1
// baseline (1372.774 us; speedup 1.0000x reference)
//
#include <hip/hip_runtime.h>
#include <hip/hip_bf16.h>
#include <cstdint>

#define DIMC 64
#define NEXP 6
#define BB 8
#define HH 128
#define WW 128
#define HWSZ (HH*WW)

// conv tiling
#define HT 32
#define WT 64
#define CINC 4

__device__ __forceinline__ float gelu_tanh(float x) {
    // jax.nn.gelu default: approximate=True (tanh form)
    float u = 0.7978845608028654f * (x + 0.044715f * x * x * x);
    return 0.5f * x * (1.0f + tanhf(u));
}

// ---------------- pool: pooled[b][c] = mean_{h,w} x[b][c][h][w] ----------------
__global__ __launch_bounds__(256) void pool_kernel(const float* __restrict__ x,
                                                   float* __restrict__ pooled) {
    int bc = blockIdx.x;  // 0..511  (b*64+c)
    const float4* p4 = reinterpret_cast<const float4*>(x + (size_t)bc * HWSZ);
    float s = 0.f;
    for (int i = threadIdx.x; i < HWSZ / 4; i += 256) {
        float4 v = p4[i];
        s += (v.x + v.y) + (v.z + v.w);
    }
#pragma unroll
    for (int off = 32; off > 0; off >>= 1) s += __shfl_down(s, off, 64);
    __shared__ float red[4];
    if ((threadIdx.x & 63) == 0) red[threadIdx.x >> 6] = s;
    __syncthreads();
    if (threadIdx.x == 0)
        pooled[bc] = (red[0] + red[1] + red[2] + red[3]) * (1.0f / (float)HWSZ);
}

// ---------------- router: logits -> clamp -> +bias -> softmax -> clip -> top2 ----
__global__ void router_kernel(const float* __restrict__ pooled,
                              const float* __restrict__ rw,
                              const float* __restrict__ rb,
                              const float* __restrict__ eb,
                              int* __restrict__ topi,
                              float* __restrict__ topw,
                              float* __restrict__ outz) {
    int b = threadIdx.x;
    // reference returns a tuple (out, scalar 0); d_out is poisoned 0xAA -> write the 0.
    if (b == 8) outz[(size_t)BB * DIMC * HWSZ] = 0.f;
    if (b >= BB) return;
    float lg[NEXP];
    for (int e = 0; e < NEXP; ++e) {
        float s = rb[e];
        for (int c = 0; c < DIMC; ++c) s += pooled[b * DIMC + c] * rw[e * DIMC + c];
        s = fminf(fmaxf(s, -10.f), 10.f) + eb[e];
        lg[e] = s;
    }
    float m = lg[0];
    for (int e = 1; e < NEXP; ++e) m = fmaxf(m, lg[e]);
    float den = 0.f;
    float pr[NEXP];
    for (int e = 0; e < NEXP; ++e) { pr[e] = expf(lg[e] - m); den += pr[e]; }
    float inv = 1.0f / den;
    for (int e = 0; e < NEXP; ++e) pr[e] = fminf(fmaxf(pr[e] * inv, 1e-6f), 1.0f);
    int i0 = 0; float v0 = pr[0];
    for (int e = 1; e < NEXP; ++e) { if (pr[e] > v0) { v0 = pr[e]; i0 = e; } }
    int i1 = -1; float v1 = -1.f;
    for (int e = 0; e < NEXP; ++e) { if (e == i0) continue; if (pr[e] > v1) { v1 = pr[e]; i1 = e; } }
    float s2 = v0 + v1 + 1e-8f;
    topi[b * 2 + 0] = i0; topi[b * 2 + 1] = i1;
    topw[b * 2 + 0] = v0 / s2; topw[b * 2 + 1] = v1 / s2;
}

// ---------------- direct 3x3 conv, expert-indirect -----------------------------
// grid: (tile 0..7 [4 h-tiles x 2 w-tiles], c_out group 0..7, pair p)
// block: 256 threads; tile 32x64 px; 8 px/thread (one row strip), 8 c_out/block.
// IS1: reads fp32 x, writes bf16 gelu(conv+b1) to hbuf.
// !IS1: reads bf16 h, writes/accumulates cw*(conv+b2) into fp32 out.
template <bool IS1>
__global__ __launch_bounds__(256) void conv_kernel(
    const float* __restrict__ inF,
    const __hip_bfloat16* __restrict__ inH,
    const float* __restrict__ wgt,   // [6][64][64][3][3]
    const float* __restrict__ bias,  // [6][64]
    const int* __restrict__ topi,
    const float* __restrict__ topw,
    __hip_bfloat16* __restrict__ outH,
    float* __restrict__ outF,
    int nslots, int slot0, int addmode) {
    __shared__ float ltile[CINC][34][68];  // rows h0-1..h0+32, cols w0-1..w0+64 (stride 68 for b128 alignment)
    __shared__ float lw[8][CINC][12];      // 9 weights padded to 12 for float4 reads

    const int t  = blockIdx.x;
    const int cg = blockIdx.y;
    const int p  = blockIdx.z;
    const int b  = p / nslots;
    const int sl = p - b * nslots;  // slot buffer index within this launch
    const int s  = slot0 + sl;      // top-k slot
    const int e  = topi[b * 2 + s];
    const int th = t >> 1, tw = t & 1;
    const int h0 = th * HT, w0 = tw * WT;
    const int tid = threadIdx.x;
    const int r = tid >> 3, g = tid & 7;

    float acc[8][8];
#pragma unroll
    for (int i = 0; i < 8; ++i)
#pragma unroll
        for (int j = 0; j < 8; ++j) acc[i][j] = 0.f;

    const size_t inbase = (size_t)b * DIMC * HWSZ;

    for (int cb = 0; cb < DIMC; cb += CINC) {
        // stage input tile (with SAME zero-halo)
        for (int idx = tid; idx < CINC * 34 * 66; idx += 256) {
            int c   = idx / (34 * 66);
            int rem = idx - c * (34 * 66);
            int rr  = rem / 66;
            int cc  = rem - rr * 66;
            int gh = h0 + rr - 1;
            int gw = w0 + cc - 1;
            float v = 0.f;
            if ((unsigned)gh < HH && (unsigned)gw < WW) {
                size_t off = inbase + (size_t)(cb + c) * HWSZ + (size_t)gh * WW + gw;
                v = IS1 ? inF[off] : __bfloat162float(inH[off]);
            }
            ltile[c][rr][cc] = v;
        }
        // stage weights for (e, c_out group, c_in chunk)
        for (int idx = tid; idx < 8 * CINC * 9; idx += 256) {
            int i   = idx / (CINC * 9);
            int rem = idx - i * (CINC * 9);
            int j   = rem / 9;
            int k   = rem - j * 9;
            lw[i][j][k] = wgt[(((size_t)e * DIMC + cg * 8 + i) * DIMC + (cb + j)) * 9 + k];
        }
        __syncthreads();

        for (int ci = 0; ci < CINC; ++ci) {
            float inr[3][12];
#pragma unroll
            for (int dr = 0; dr < 3; ++dr) {
                const float4* rp = reinterpret_cast<const float4*>(&ltile[ci][r + dr][g * 8]);
                float4 a = rp[0], bq = rp[1], cq = rp[2];
                inr[dr][0] = a.x;  inr[dr][1] = a.y;  inr[dr][2] = a.z;  inr[dr][3] = a.w;
                inr[dr][4] = bq.x; inr[dr][5] = bq.y; inr[dr][6] = bq.z; inr[dr][7] = bq.w;
                inr[dr][8] = cq.x; inr[dr][9] = cq.y; inr[dr][10] = cq.z; inr[dr][11] = cq.w;
            }
#pragma unroll
            for (int co = 0; co < 8; ++co) {
                const float4* wp = reinterpret_cast<const float4*>(&lw[co][ci][0]);
                float4 wa = wp[0], wb = wp[1], wc = wp[2];
                float q0 = wa.x, q1 = wa.y, q2 = wa.z;
                float q3 = wa.w, q4 = wb.x, q5 = wb.y;
                float q6 = wb.z, q7 = wb.w, q8 = wc.x;
#pragma unroll
                for (int i = 0; i < 8; ++i) {
                    float v = acc[co][i];
                    v += q0 * inr[0][i] + q1 * inr[0][i + 1] + q2 * inr[0][i + 2];
                    v += q3 * inr[1][i] + q4 * inr[1][i + 1] + q5 * inr[1][i + 2];
                    v += q6 * inr[2][i] + q7 * inr[2][i + 1] + q8 * inr[2][i + 2];
                    acc[co][i] = v;
                }
            }
        }
        __syncthreads();
    }

    const int hh = h0 + r;
    const int wbase = w0 + g * 8;
    if (IS1) {
        const size_t obase = ((size_t)sl * BB + b) * DIMC * HWSZ;
#pragma unroll
        for (int co = 0; co < 8; ++co) {
            float bv = bias[e * DIMC + cg * 8 + co];
            union { __hip_bfloat16 hv[8]; float4 f4; } u;
#pragma unroll
            for (int i = 0; i < 8; ++i)
                u.hv[i] = __float2bfloat16(gelu_tanh(acc[co][i] + bv));
            *reinterpret_cast<float4*>(outH + obase + (size_t)(cg * 8 + co) * HWSZ +
                                       (size_t)hh * WW + wbase) = u.f4;
        }
    } else {
        const float cw = topw[b * 2 + s];
        const size_t obase = (size_t)b * DIMC * HWSZ;
#pragma unroll
        for (int co = 0; co < 8; ++co) {
            float bv = bias[e * DIMC + cg * 8 + co];
            float4* dst = reinterpret_cast<float4*>(outF + obase + (size_t)(cg * 8 + co) * HWSZ +
                                                    (size_t)hh * WW + wbase);
            float4 o0, o1;
            o0.x = cw * (acc[co][0] + bv); o0.y = cw * (acc[co][1] + bv);
            o0.z = cw * (acc[co][2] + bv); o0.w = cw * (acc[co][3] + bv);
            o1.x = cw * (acc[co][4] + bv); o1.y = cw * (acc[co][5] + bv);
            o1.z = cw * (acc[co][6] + bv); o1.w = cw * (acc[co][7] + bv);
            if (addmode) {
                float4 a0 = dst[0], a1 = dst[1];
                o0.x += a0.x; o0.y += a0.y; o0.z += a0.z; o0.w += a0.w;
                o1.x += a1.x; o1.y += a1.y; o1.z += a1.z; o1.w += a1.w;
            }
            dst[0] = o0; dst[1] = o1;
        }
    }
}

extern "C" void kernel_launch(void* const* d_in, const int* in_sizes, int n_in,
                              void* d_out, int out_size, void* d_ws, size_t ws_size,
                              hipStream_t stream) {
    const float* x  = (const float*)d_in[0];
    const float* rw = (const float*)d_in[1];
    const float* rb = (const float*)d_in[2];
    const float* eb = (const float*)d_in[3];
    const float* w1 = (const float*)d_in[4];
    const float* b1 = (const float*)d_in[5];
    const float* w2 = (const float*)d_in[6];
    const float* b2 = (const float*)d_in[7];
    float* out = (float*)d_out;

    char* ws = (char*)d_ws;
    float* pooled = (float*)ws;                       // 512 floats
    int*   topi   = (int*)(ws + 2048);                // [8][2]
    float* topw   = (float*)(ws + 2112);              // [8][2]
    __hip_bfloat16* hbuf = (__hip_bfloat16*)(ws + 4096);
    const size_t HSLOT = (size_t)BB * DIMC * HWSZ;    // elements per h slot

    const bool full = ws_size >= (size_t)4096 + 2 * HSLOT * sizeof(__hip_bfloat16);

    hipLaunchKernelGGL(pool_kernel, dim3(BB * DIMC), dim3(256), 0, stream, x, pooled);
    hipLaunchKernelGGL(router_kernel, dim3(1), dim3(64), 0, stream,
                       pooled, rw, rb, eb, topi, topw, out);

    if (full) {
        // conv1 over both slots at once (16 pairs), then conv2 per slot (slot1 accumulates)
        hipLaunchKernelGGL((conv_kernel<true>), dim3(8, 8, 16), dim3(256), 0, stream,
                           x, (const __hip_bfloat16*)nullptr, w1, b1, topi, topw,
                           hbuf, (float*)nullptr, 2, 0, 0);
        hipLaunchKernelGGL((conv_kernel<false>), dim3(8, 8, 8), dim3(256), 0, stream,
                           (const float*)nullptr, hbuf, w2, b2, topi, topw,
                           (__hip_bfloat16*)nullptr, out, 1, 0, 0);
        hipLaunchKernelGGL((conv_kernel<false>), dim3(8, 8, 8), dim3(256), 0, stream,
                           (const float*)nullptr, hbuf + HSLOT, w2, b2, topi, topw,
                           (__hip_bfloat16*)nullptr, out, 1, 1, 1);
    } else {
        // fallback: single h buffer, fully sequential per slot
        hipLaunchKernelGGL((conv_kernel<true>), dim3(8, 8, 8), dim3(256), 0, stream,
                           x, (const __hip_bfloat16*)nullptr, w1, b1, topi, topw,
                           hbuf, (float*)nullptr, 1, 0, 0);
        hipLaunchKernelGGL((conv_kernel<false>), dim3(8, 8, 8), dim3(256), 0, stream,
                           (const float*)nullptr, hbuf, w2, b2, topi, topw,
                           (__hip_bfloat16*)nullptr, out, 1, 0, 0);
        hipLaunchKernelGGL((conv_kernel<true>), dim3(8, 8, 8), dim3(256), 0, stream,
                           x, (const __hip_bfloat16*)nullptr, w1, b1, topi, topw,
                           hbuf, (float*)nullptr, 1, 1, 0);
        hipLaunchKernelGGL((conv_kernel<false>), dim3(8, 8, 8), dim3(256), 0, stream,
                           (const float*)nullptr, hbuf, w2, b2, topi, topw,
                           (__hip_bfloat16*)nullptr, out, 1, 1, 1);
    }
}

// Round 2
// 317.775 us; speedup vs baseline: 4.3200x; 4.3200x over previous
//
#include <hip/hip_runtime.h>
#include <hip/hip_bf16.h>
#include <cstdint>

typedef __attribute__((ext_vector_type(8))) short sh8;
typedef __attribute__((ext_vector_type(16))) float f32x16;
typedef unsigned short ushort_t;

#define HH 128
#define WW 128
#define HWSZ (HH*WW)
#define PW 130
#define IMGSZ ((size_t)PW*PW*64)   // padded NHWC image, elements

__device__ __forceinline__ float gelu_tanh(float x) {
    float u = 0.7978845608028654f * (x + 0.044715f * x * x * x);
    return 0.5f * x * (1.0f + tanhf(u));
}
__device__ __forceinline__ ushort_t f2b(float f) {
    __hip_bfloat16 h = __float2bfloat16(f);
    return *reinterpret_cast<ushort_t*>(&h);
}

// ---------------- pool ----------------
__global__ __launch_bounds__(256) void pool_kernel(const float* __restrict__ x,
                                                   float* __restrict__ pooled) {
    int bc = blockIdx.x;  // b*64+c
    const float4* p4 = reinterpret_cast<const float4*>(x + (size_t)bc * HWSZ);
    float s = 0.f;
    for (int i = threadIdx.x; i < HWSZ / 4; i += 256) {
        float4 v = p4[i];
        s += (v.x + v.y) + (v.z + v.w);
    }
#pragma unroll
    for (int off = 32; off > 0; off >>= 1) s += __shfl_down(s, off, 64);
    __shared__ float red[4];
    if ((threadIdx.x & 63) == 0) red[threadIdx.x >> 6] = s;
    __syncthreads();
    if (threadIdx.x == 0)
        pooled[bc] = (red[0] + red[1] + red[2] + red[3]) * (1.0f / (float)HWSZ);
}

// ---------------- router (+bsum, +tuple-tail zero) ----------------
__global__ __launch_bounds__(64) void router_kernel(const float* __restrict__ pooled,
                                                    const float* __restrict__ rw,
                                                    const float* __restrict__ rb,
                                                    const float* __restrict__ eb,
                                                    const float* __restrict__ b2,
                                                    int* __restrict__ topi,
                                                    float* __restrict__ topw,
                                                    float* __restrict__ bsum,
                                                    float* __restrict__ outz) {
    __shared__ int sti[16];
    __shared__ float stw[16];
    int b = threadIdx.x;
    if (b == 8) outz[(size_t)8 * 64 * HWSZ] = 0.f;  // tuple's scalar 0
    if (b < 8) {
        float lg[6];
        for (int e = 0; e < 6; ++e) {
            float s = rb[e];
            for (int c = 0; c < 64; ++c) s += pooled[b * 64 + c] * rw[e * 64 + c];
            lg[e] = fminf(fmaxf(s, -10.f), 10.f) + eb[e];
        }
        float m = lg[0];
        for (int e = 1; e < 6; ++e) m = fmaxf(m, lg[e]);
        float den = 0.f, pr[6];
        for (int e = 0; e < 6; ++e) { pr[e] = expf(lg[e] - m); den += pr[e]; }
        float inv = 1.0f / den;
        for (int e = 0; e < 6; ++e) pr[e] = fminf(fmaxf(pr[e] * inv, 1e-6f), 1.0f);
        int i0 = 0; float v0 = pr[0];
        for (int e = 1; e < 6; ++e) if (pr[e] > v0) { v0 = pr[e]; i0 = e; }
        int i1 = -1; float v1 = -1.f;
        for (int e = 0; e < 6; ++e) { if (e == i0) continue; if (pr[e] > v1) { v1 = pr[e]; i1 = e; } }
        float s2 = v0 + v1 + 1e-8f;
        topi[b * 2 + 0] = i0; topi[b * 2 + 1] = i1;
        topw[b * 2 + 0] = v0 / s2; topw[b * 2 + 1] = v1 / s2;
        sti[b * 2 + 0] = i0; sti[b * 2 + 1] = i1;
        stw[b * 2 + 0] = v0 / s2; stw[b * 2 + 1] = v1 / s2;
    }
    __syncthreads();
    for (int i = threadIdx.x; i < 512; i += 64) {
        int bb = i >> 6, c = i & 63;
        bsum[i] = stw[bb * 2] * b2[sti[bb * 2] * 64 + c] +
                  stw[bb * 2 + 1] * b2[sti[bb * 2 + 1] * 64 + c];
    }
}

// ------------- x: NCHW fp32 -> padded NHWC bf16 -------------
__global__ __launch_bounds__(256) void convx_kernel(const float* __restrict__ x,
                                                    ushort_t* __restrict__ xp) {
    __shared__ ushort_t lt[128][72];
    int b = blockIdx.x >> 7, h = blockIdx.x & 127;
    int tid = threadIdx.x;
#pragma unroll
    for (int k = 0; k < 8; ++k) {
        int idx = tid + k * 256;            // 0..2047
        int ci = idx >> 5, wg = idx & 31;
        float4 v = *reinterpret_cast<const float4*>(
            x + ((size_t)b * 64 + ci) * HWSZ + (size_t)h * WW + wg * 4);
        lt[wg * 4 + 0][ci] = f2b(v.x);
        lt[wg * 4 + 1][ci] = f2b(v.y);
        lt[wg * 4 + 2][ci] = f2b(v.z);
        lt[wg * 4 + 3][ci] = f2b(v.w);
    }
    __syncthreads();
    int w = tid >> 1, half = tid & 1;
    const int4* src = reinterpret_cast<const int4*>(&lt[w][half * 32]);
    int4 a0 = src[0], a1 = src[1], a2 = src[2], a3 = src[3];
    int4* dst = reinterpret_cast<int4*>(
        xp + (((size_t)b * PW + (h + 1)) * PW + (w + 1)) * 64 + half * 32);
    dst[0] = a0; dst[1] = a1; dst[2] = a2; dst[3] = a3;
}

// ------------- w1 -> [e][tap][co][ci] bf16 -------------
__global__ __launch_bounds__(64) void convw1_kernel(const float* __restrict__ w1,
                                                    ushort_t* __restrict__ wb1) {
    int eco = blockIdx.x;        // e*64+co, 384 blocks
    int ci = threadIdx.x;
    const float* src = w1 + ((size_t)eco * 64 + ci) * 9;
    int e = eco >> 6, co = eco & 63;
#pragma unroll
    for (int t = 0; t < 9; ++t)
        wb1[(((size_t)e * 9 + t) * 64 + co) * 64 + ci] = f2b(src[t]);
}

// ------------- w2 -> cw-scaled [b*2+s][tap][co][ci] bf16 -------------
__global__ __launch_bounds__(64) void convw2_kernel(const float* __restrict__ w2,
                                                    const int* __restrict__ topi,
                                                    const float* __restrict__ topw,
                                                    ushort_t* __restrict__ wb2) {
    int g = blockIdx.x;          // 1024: (b*2+s)*64 + co
    int ci = threadIdx.x;
    int co = g & 63, bs = g >> 6;
    int e = topi[bs];
    float cw = topw[bs];
    const float* src = w2 + (((size_t)e * 64 + co) * 64 + ci) * 9;
#pragma unroll
    for (int t = 0; t < 9; ++t)
        wb2[((size_t)bs * 9 + t) * 4096 + co * 64 + ci] = f2b(cw * src[t]);
}

// ------------- zero the halo of a padded NHWC image -------------
__global__ __launch_bounds__(256) void halo_kernel(ushort_t* __restrict__ buf) {
    ushort_t* p = buf + (size_t)blockIdx.x * IMGSZ;
    int tid = threadIdx.x;
    int4 z = make_int4(0, 0, 0, 0);
    for (int i = tid; i < 1040; i += 256) {          // top + bottom rows (130*64 shorts = 1040 int4)
        reinterpret_cast<int4*>(p)[i] = z;
        reinterpret_cast<int4*>(p + (size_t)129 * PW * 64)[i] = z;
    }
    for (int i = tid; i < 128 * 8; i += 256) {       // left + right cols
        int row = 1 + (i >> 3), j = i & 7;
        reinterpret_cast<int4*>(p + (size_t)row * PW * 64)[j] = z;
        reinterpret_cast<int4*>(p + ((size_t)row * PW + 129) * 64)[j] = z;
    }
}

// ------------- conv1: xp -> gelu(conv+b1) -> hp (padded NHWC bf16) -------------
__global__ __launch_bounds__(256) void conv1_mfma(const ushort_t* __restrict__ xp,
                                                  const ushort_t* __restrict__ wb1,
                                                  const float* __restrict__ b1,
                                                  const int* __restrict__ topi,
                                                  ushort_t* __restrict__ hp,
                                                  int nslots, int slot0) {
    const int z = blockIdx.z;
    const int b = z / nslots, sl = z - b * nslots, s = slot0 + sl;
    const int e = topi[b * 2 + s];
    const int tid = threadIdx.x, l = tid & 63, wid = tid >> 6;
    const int n = wid & 1, rp = wid >> 1;
    const int hgrp = blockIdx.x >> 2, w0 = (blockIdx.x & 3) * 32;
    const int l31 = l & 31, lh = l >> 5;

    const ushort_t* wbE = wb1 + (size_t)e * 36864;
    const int boff = (n * 32 + l31) * 64 + lh * 8;
    sh8 Bf[9][4];
#pragma unroll
    for (int t = 0; t < 9; ++t)
#pragma unroll
        for (int kc = 0; kc < 4; ++kc)
            Bf[t][kc] = *reinterpret_cast<const sh8*>(wbE + t * 4096 + kc * 16 + boff);

    const int aoff = l31 * 64 + lh * 8;
    const float bv = b1[e * 64 + n * 32 + l31];

    for (int i = 0; i < 4; ++i) {
        const int h = hgrp * 8 + rp * 4 + i;
        // padded row for dr=-1 is (h+dr+1) = h
        const ushort_t* ar0 = xp + ((size_t)b * PW + h) * (size_t)PW * 64 + (size_t)w0 * 64;
        f32x16 acc;
#pragma unroll
        for (int k2 = 0; k2 < 16; ++k2) acc[k2] = 0.f;
#pragma unroll
        for (int t = 0; t < 9; ++t) {
            const int dr = t / 3, dc = t - dr * 3;
            const ushort_t* ap = ar0 + (size_t)dr * PW * 64 + aoff + dc * 64;
#pragma unroll
            for (int kc = 0; kc < 4; ++kc) {
                sh8 a = *reinterpret_cast<const sh8*>(ap + kc * 16);
                acc = __builtin_amdgcn_mfma_f32_32x32x16_bf16(a, Bf[t][kc], acc, 0, 0, 0);
            }
        }
        const size_t obase =
            (((size_t)(sl * 8 + b) * PW + (h + 1)) * PW + (w0 + 1)) * 64 + n * 32 + l31;
#pragma unroll
        for (int r = 0; r < 16; ++r) {
            int px = (r & 3) + 8 * (r >> 2) + 4 * lh;
            hp[obase + (size_t)px * 64] = f2b(gelu_tanh(acc[r] + bv));
        }
    }
}

// ------------- conv2: hp -> cw*conv (+bsum) -> out NCHW fp32 -------------
__global__ __launch_bounds__(256) void conv2_mfma(const ushort_t* __restrict__ hpS,
                                                  const ushort_t* __restrict__ wbS,
                                                  const float* __restrict__ bsum,
                                                  float* __restrict__ outF,
                                                  int addmode) {
    __shared__ float lt[4][32][33];
    const int b = blockIdx.z;
    const int tid = threadIdx.x, l = tid & 63, wid = tid >> 6;
    const int n = wid & 1, rp = wid >> 1;
    const int hgrp = blockIdx.x >> 2, w0 = (blockIdx.x & 3) * 32;
    const int l31 = l & 31, lh = l >> 5;

    const ushort_t* wbE = wbS + (size_t)b * 73728;
    const int boff = (n * 32 + l31) * 64 + lh * 8;
    sh8 Bf[9][4];
#pragma unroll
    for (int t = 0; t < 9; ++t)
#pragma unroll
        for (int kc = 0; kc < 4; ++kc)
            Bf[t][kc] = *reinterpret_cast<const sh8*>(wbE + t * 4096 + kc * 16 + boff);

    const int aoff = l31 * 64 + lh * 8;
    const float bq = addmode ? 0.f : bsum[b * 64 + n * 32 + l31];

    for (int i = 0; i < 4; ++i) {
        const int h = hgrp * 8 + rp * 4 + i;
        const ushort_t* ar0 = hpS + ((size_t)b * PW + h) * (size_t)PW * 64 + (size_t)w0 * 64;
        f32x16 acc;
#pragma unroll
        for (int k2 = 0; k2 < 16; ++k2) acc[k2] = 0.f;
#pragma unroll
        for (int t = 0; t < 9; ++t) {
            const int dr = t / 3, dc = t - dr * 3;
            const ushort_t* ap = ar0 + (size_t)dr * PW * 64 + aoff + dc * 64;
#pragma unroll
            for (int kc = 0; kc < 4; ++kc) {
                sh8 a = *reinterpret_cast<const sh8*>(ap + kc * 16);
                acc = __builtin_amdgcn_mfma_f32_32x32x16_bf16(a, Bf[t][kc], acc, 0, 0, 0);
            }
        }
        // transpose 32px x 32co through LDS (wave-local), emit NCHW float4
#pragma unroll
        for (int r = 0; r < 16; ++r) {
            int px = (r & 3) + 8 * (r >> 2) + 4 * lh;
            lt[wid][px][l31] = acc[r] + bq;
        }
        const int q = lh, co = l31;
        const size_t ob = ((size_t)(b * 64 + n * 32 + co)) * HWSZ + (size_t)h * WW + w0 + q * 16;
#pragma unroll
        for (int v = 0; v < 4; ++v) {
            float o0 = lt[wid][q * 16 + v * 4 + 0][co];
            float o1 = lt[wid][q * 16 + v * 4 + 1][co];
            float o2 = lt[wid][q * 16 + v * 4 + 2][co];
            float o3 = lt[wid][q * 16 + v * 4 + 3][co];
            float4* dst = reinterpret_cast<float4*>(outF + ob + v * 4);
            if (addmode) {
                float4 pv = *dst;
                o0 += pv.x; o1 += pv.y; o2 += pv.z; o3 += pv.w;
            }
            float4 o; o.x = o0; o.y = o1; o.z = o2; o.w = o3;
            *dst = o;
        }
    }
}

extern "C" void kernel_launch(void* const* d_in, const int* in_sizes, int n_in,
                              void* d_out, int out_size, void* d_ws, size_t ws_size,
                              hipStream_t stream) {
    const float* x  = (const float*)d_in[0];
    const float* rw = (const float*)d_in[1];
    const float* rb = (const float*)d_in[2];
    const float* eb = (const float*)d_in[3];
    const float* w1 = (const float*)d_in[4];
    const float* b1 = (const float*)d_in[5];
    const float* w2 = (const float*)d_in[6];
    const float* b2 = (const float*)d_in[7];
    float* out = (float*)d_out;

    char* ws = (char*)d_ws;
    float*    pooled = (float*)(ws + 0);
    int*      topi   = (int*)(ws + 2048);
    float*    topw   = (float*)(ws + 2112);
    float*    bsum   = (float*)(ws + 2176);
    ushort_t* wb1    = (ushort_t*)(ws + 4352);
    ushort_t* wb2    = (ushort_t*)(ws + 446720);
    ushort_t* xp     = (ushort_t*)(ws + 1626368);
    ushort_t* hp     = (ushort_t*)(ws + 18931968);

    const bool two = ws_size >= 53543168ull;  // hp holds both slots?

    hipLaunchKernelGGL(pool_kernel, dim3(512), dim3(256), 0, stream, x, pooled);
    hipLaunchKernelGGL(router_kernel, dim3(1), dim3(64), 0, stream,
                       pooled, rw, rb, eb, b2, topi, topw, bsum, out);
    hipLaunchKernelGGL(convx_kernel, dim3(1024), dim3(256), 0, stream, x, xp);
    hipLaunchKernelGGL(convw1_kernel, dim3(384), dim3(64), 0, stream, w1, wb1);
    hipLaunchKernelGGL(convw2_kernel, dim3(1024), dim3(64), 0, stream, w2, topi, topw, wb2);
    hipLaunchKernelGGL(halo_kernel, dim3(8), dim3(256), 0, stream, xp);
    hipLaunchKernelGGL(halo_kernel, dim3(two ? 16 : 8), dim3(256), 0, stream, hp);

    if (two) {
        hipLaunchKernelGGL(conv1_mfma, dim3(64, 1, 16), dim3(256), 0, stream,
                           xp, wb1, b1, topi, hp, 2, 0);
        hipLaunchKernelGGL(conv2_mfma, dim3(64, 1, 8), dim3(256), 0, stream,
                           hp, wb2, bsum, out, 0);
        hipLaunchKernelGGL(conv2_mfma, dim3(64, 1, 8), dim3(256), 0, stream,
                           hp + 8 * IMGSZ, wb2 + 36864, bsum, out, 1);
    } else {
        hipLaunchKernelGGL(conv1_mfma, dim3(64, 1, 8), dim3(256), 0, stream,
                           xp, wb1, b1, topi, hp, 1, 0);
        hipLaunchKernelGGL(conv2_mfma, dim3(64, 1, 8), dim3(256), 0, stream,
                           hp, wb2, bsum, out, 0);
        hipLaunchKernelGGL(conv1_mfma, dim3(64, 1, 8), dim3(256), 0, stream,
                           xp, wb1, b1, topi, hp, 1, 1);
        hipLaunchKernelGGL(conv2_mfma, dim3(64, 1, 8), dim3(256), 0, stream,
                           hp, wb2 + 36864, bsum, out, 1);
    }
}

// Round 3
// 256.398 us; speedup vs baseline: 5.3541x; 1.2394x over previous
//
#include <hip/hip_runtime.h>
#include <hip/hip_bf16.h>
#include <cstdint>

typedef __attribute__((ext_vector_type(8))) short sh8;
typedef __attribute__((ext_vector_type(16))) float f32x16;
typedef unsigned short ushort_t;

#define HH 128
#define WW 128
#define HWSZ (HH*WW)
#define PW 130
#define PW64 (PW*64)
#define IMGSZ ((size_t)PW*PW*64)   // padded NHWC image, elements
#define WBEXP 36864                // elems per packed weight set: 9*4*2*512

__device__ __forceinline__ float gelu_tanh(float x) {
    float u = 0.7978845608028654f * (x + 0.044715f * x * x * x);
    return 0.5f * x * (1.0f + tanhf(u));
}
__device__ __forceinline__ ushort_t f2b(float f) {
    __hip_bfloat16 h = __float2bfloat16(f);
    return *reinterpret_cast<ushort_t*>(&h);
}
__device__ __forceinline__ f32x16 mfma_bf16(sh8 a, sh8 b, f32x16 c) {
    return __builtin_amdgcn_mfma_f32_32x32x16_bf16(a, b, c, 0, 0, 0);
}

// ---------------- pool ----------------
__global__ __launch_bounds__(256) void pool_kernel(const float* __restrict__ x,
                                                   float* __restrict__ pooled) {
    int bc = blockIdx.x;  // b*64+c
    const float4* p4 = reinterpret_cast<const float4*>(x + (size_t)bc * HWSZ);
    float s = 0.f;
    for (int i = threadIdx.x; i < HWSZ / 4; i += 256) {
        float4 v = p4[i];
        s += (v.x + v.y) + (v.z + v.w);
    }
#pragma unroll
    for (int off = 32; off > 0; off >>= 1) s += __shfl_down(s, off, 64);
    __shared__ float red[4];
    if ((threadIdx.x & 63) == 0) red[threadIdx.x >> 6] = s;
    __syncthreads();
    if (threadIdx.x == 0)
        pooled[bc] = (red[0] + red[1] + red[2] + red[3]) * (1.0f / (float)HWSZ);
}

// ---------------- router (+bsum, +tuple-tail zero) ----------------
__global__ __launch_bounds__(64) void router_kernel(const float* __restrict__ pooled,
                                                    const float* __restrict__ rw,
                                                    const float* __restrict__ rb,
                                                    const float* __restrict__ eb,
                                                    const float* __restrict__ b2,
                                                    int* __restrict__ topi,
                                                    float* __restrict__ topw,
                                                    float* __restrict__ bsum,
                                                    float* __restrict__ outz) {
    __shared__ int sti[16];
    __shared__ float stw[16];
    int b = threadIdx.x;
    if (b == 8) outz[(size_t)8 * 64 * HWSZ] = 0.f;  // tuple's scalar 0
    if (b < 8) {
        float lg[6];
        for (int e = 0; e < 6; ++e) {
            float s = rb[e];
            for (int c = 0; c < 64; ++c) s += pooled[b * 64 + c] * rw[e * 64 + c];
            lg[e] = fminf(fmaxf(s, -10.f), 10.f) + eb[e];
        }
        float m = lg[0];
        for (int e = 1; e < 6; ++e) m = fmaxf(m, lg[e]);
        float den = 0.f, pr[6];
        for (int e = 0; e < 6; ++e) { pr[e] = expf(lg[e] - m); den += pr[e]; }
        float inv = 1.0f / den;
        for (int e = 0; e < 6; ++e) pr[e] = fminf(fmaxf(pr[e] * inv, 1e-6f), 1.0f);
        int i0 = 0; float v0 = pr[0];
        for (int e = 1; e < 6; ++e) if (pr[e] > v0) { v0 = pr[e]; i0 = e; }
        int i1 = -1; float v1 = -1.f;
        for (int e = 0; e < 6; ++e) { if (e == i0) continue; if (pr[e] > v1) { v1 = pr[e]; i1 = e; } }
        float s2 = v0 + v1 + 1e-8f;
        topi[b * 2 + 0] = i0; topi[b * 2 + 1] = i1;
        topw[b * 2 + 0] = v0 / s2; topw[b * 2 + 1] = v1 / s2;
        sti[b * 2 + 0] = i0; sti[b * 2 + 1] = i1;
        stw[b * 2 + 0] = v0 / s2; stw[b * 2 + 1] = v1 / s2;
    }
    __syncthreads();
    for (int i = threadIdx.x; i < 512; i += 64) {
        int bb = i >> 6, c = i & 63;
        bsum[i] = stw[bb * 2] * b2[sti[bb * 2] * 64 + c] +
                  stw[bb * 2 + 1] * b2[sti[bb * 2 + 1] * 64 + c];
    }
}

// ------------- x: NCHW fp32 -> padded NHWC bf16 -------------
__global__ __launch_bounds__(256) void convx_kernel(const float* __restrict__ x,
                                                    ushort_t* __restrict__ xp) {
    __shared__ ushort_t lt[128][72];
    int b = blockIdx.x >> 7, h = blockIdx.x & 127;
    int tid = threadIdx.x;
#pragma unroll
    for (int k = 0; k < 8; ++k) {
        int idx = tid + k * 256;            // 0..2047
        int ci = idx >> 5, wg = idx & 31;
        float4 v = *reinterpret_cast<const float4*>(
            x + ((size_t)b * 64 + ci) * HWSZ + (size_t)h * WW + wg * 4);
        lt[wg * 4 + 0][ci] = f2b(v.x);
        lt[wg * 4 + 1][ci] = f2b(v.y);
        lt[wg * 4 + 2][ci] = f2b(v.z);
        lt[wg * 4 + 3][ci] = f2b(v.w);
    }
    __syncthreads();
    int w = tid >> 1, half = tid & 1;
    const int4* src = reinterpret_cast<const int4*>(&lt[w][half * 32]);
    int4 a0 = src[0], a1 = src[1], a2 = src[2], a3 = src[3];
    int4* dst = reinterpret_cast<int4*>(
        xp + (((size_t)b * PW + (h + 1)) * PW + (w + 1)) * 64 + half * 32);
    dst[0] = a0; dst[1] = a1; dst[2] = a2; dst[3] = a3;
}

// ------------- w1 -> fragment-linear bf16: [e][t][kc][n][lane][8] -------------
__global__ __launch_bounds__(256) void convw1_kernel(const float* __restrict__ w1,
                                                     ushort_t* __restrict__ wb1f) {
    int blk = blockIdx.x;          // e*9+t, 54 blocks
    int e = blk / 9, t = blk - e * 9;
    for (int idx = threadIdx.x; idx < 4096; idx += 256) {
        int kc = idx >> 10, n = (idx >> 9) & 1, l = (idx >> 3) & 63, j = idx & 7;
        int co = n * 32 + (l & 31);
        int ci = kc * 16 + (l >> 5) * 8 + j;
        wb1f[(size_t)e * WBEXP + t * 4096 + idx] =
            f2b(w1[(((size_t)e * 64 + co) * 64 + ci) * 9 + t]);
    }
}

// ------------- w2 -> cw-scaled fragment-linear bf16: [bs][t][kc][n][lane][8] ----
__global__ __launch_bounds__(256) void convw2_kernel(const float* __restrict__ w2,
                                                     const int* __restrict__ topi,
                                                     const float* __restrict__ topw,
                                                     ushort_t* __restrict__ wb2f) {
    int blk = blockIdx.x;          // bs*9+t, 144 blocks
    int bs = blk / 9, t = blk - bs * 9;
    int e = topi[bs];
    float cw = topw[bs];
    for (int idx = threadIdx.x; idx < 4096; idx += 256) {
        int kc = idx >> 10, n = (idx >> 9) & 1, l = (idx >> 3) & 63, j = idx & 7;
        int co = n * 32 + (l & 31);
        int ci = kc * 16 + (l >> 5) * 8 + j;
        wb2f[(size_t)bs * WBEXP + t * 4096 + idx] =
            f2b(cw * w2[(((size_t)e * 64 + co) * 64 + ci) * 9 + t]);
    }
}

// ------------- zero the halo of a padded NHWC image -------------
__global__ __launch_bounds__(256) void halo_kernel(ushort_t* __restrict__ buf) {
    ushort_t* p = buf + (size_t)blockIdx.x * IMGSZ;
    int tid = threadIdx.x;
    int4 z = make_int4(0, 0, 0, 0);
    for (int i = tid; i < 1040; i += 256) {          // top + bottom rows
        reinterpret_cast<int4*>(p)[i] = z;
        reinterpret_cast<int4*>(p + (size_t)129 * PW64)[i] = z;
    }
    for (int i = tid; i < 128 * 8; i += 256) {       // left + right cols
        int row = 1 + (i >> 3), j = i & 7;
        reinterpret_cast<int4*>(p + (size_t)row * PW64)[j] = z;
        reinterpret_cast<int4*>(p + ((size_t)row * PW + 129) * 64)[j] = z;
    }
}

// ------------- conv1: xp -> gelu(conv+b1) -> hp  (M-block = 4 rows/wave) -------
__global__ __launch_bounds__(256) void conv1_mfma(const ushort_t* __restrict__ xp,
                                                  const ushort_t* __restrict__ wb1f,
                                                  const float* __restrict__ b1,
                                                  const int* __restrict__ topi,
                                                  ushort_t* __restrict__ hp,
                                                  int nslots, int slot0) {
    const int z = blockIdx.z;
    const int b = z / nslots, sl = z - b * nslots, s = slot0 + sl;
    const int e = topi[b * 2 + s];
    const int tid = threadIdx.x, l = tid & 63, wid = tid >> 6;
    const int n = wid & 1, rp = wid >> 1;
    const int hgrp = blockIdx.x >> 2, w0 = (blockIdx.x & 3) * 32;
    const int l31 = l & 31, lh = l >> 5;
    const int h0 = hgrp * 8 + rp * 4;   // 4 output rows h0..h0+3

    const ushort_t* wbW = wb1f + (size_t)e * WBEXP + n * 512 + l * 8;
    // A base: padded row h0 (= input row h0-1), this wave's lane offset
    const ushort_t* aB = xp + (size_t)b * IMGSZ + (size_t)h0 * PW64 +
                         (size_t)w0 * 64 + l31 * 64 + lh * 8;

    f32x16 acc0, acc1, acc2, acc3;
#pragma unroll
    for (int k2 = 0; k2 < 16; ++k2) { acc0[k2] = 0.f; acc1[k2] = 0.f; acc2[k2] = 0.f; acc3[k2] = 0.f; }

#pragma unroll
    for (int dr = 0; dr < 3; ++dr) {
        const ushort_t* ar = aB + (size_t)dr * PW64;
#pragma unroll
        for (int dc = 0; dc < 3; ++dc) {
            const ushort_t* ap = ar + dc * 64;
            const int t = dr * 3 + dc;
#pragma unroll
            for (int kc = 0; kc < 4; ++kc) {
                sh8 bf = *reinterpret_cast<const sh8*>(wbW + ((size_t)(t * 4 + kc)) * 1024);
                sh8 a0 = *reinterpret_cast<const sh8*>(ap + kc * 16);
                sh8 a1 = *reinterpret_cast<const sh8*>(ap + PW64 + kc * 16);
                sh8 a2 = *reinterpret_cast<const sh8*>(ap + 2 * PW64 + kc * 16);
                sh8 a3 = *reinterpret_cast<const sh8*>(ap + 3 * PW64 + kc * 16);
                acc0 = mfma_bf16(a0, bf, acc0);
                acc1 = mfma_bf16(a1, bf, acc1);
                acc2 = mfma_bf16(a2, bf, acc2);
                acc3 = mfma_bf16(a3, bf, acc3);
            }
        }
    }

    const float bv = b1[e * 64 + n * 32 + l31];
    const size_t ob0 = (((size_t)(sl * 8 + b) * PW + (h0 + 1)) * PW + (w0 + 1)) * 64 + n * 32 + l31;
#pragma unroll
    for (int i = 0; i < 4; ++i) {
        f32x16 a = (i == 0) ? acc0 : (i == 1) ? acc1 : (i == 2) ? acc2 : acc3;
        const size_t ob = ob0 + (size_t)i * PW64;
#pragma unroll
        for (int r = 0; r < 16; ++r) {
            int px = (r & 3) + 8 * (r >> 2) + 4 * lh;
            hp[ob + (size_t)px * 64] = f2b(gelu_tanh(a[r] + bv));
        }
    }
}

// ------------- conv2: hp(slots s0..s1) -> sum cw*conv (+bsum) -> out NCHW fp32 --
__global__ __launch_bounds__(256) void conv2_mfma(const ushort_t* __restrict__ hp,
                                                  const ushort_t* __restrict__ wb2f,
                                                  const float* __restrict__ bsum,
                                                  float* __restrict__ outF,
                                                  int s0, int s1, int addmode) {
    __shared__ float lt[4][32][33];
    const int b = blockIdx.z;
    const int tid = threadIdx.x, l = tid & 63, wid = tid >> 6;
    const int n = wid & 1, rp = wid >> 1;
    const int hgrp = blockIdx.x >> 2, w0 = (blockIdx.x & 3) * 32;
    const int l31 = l & 31, lh = l >> 5;
    const int h0 = hgrp * 4 + rp * 2;   // 2 output rows

    f32x16 acc0, acc1;
#pragma unroll
    for (int k2 = 0; k2 < 16; ++k2) { acc0[k2] = 0.f; acc1[k2] = 0.f; }

    for (int s = s0; s <= s1; ++s) {
        const ushort_t* wbW = wb2f + (size_t)(b * 2 + s) * WBEXP + n * 512 + l * 8;
        const ushort_t* aB = hp + (size_t)((s - s0) * 8 + b) * IMGSZ + (size_t)h0 * PW64 +
                             (size_t)w0 * 64 + l31 * 64 + lh * 8;
#pragma unroll
        for (int dr = 0; dr < 3; ++dr) {
            const ushort_t* ar = aB + (size_t)dr * PW64;
#pragma unroll
            for (int dc = 0; dc < 3; ++dc) {
                const ushort_t* ap = ar + dc * 64;
                const int t = dr * 3 + dc;
#pragma unroll
                for (int kc = 0; kc < 4; ++kc) {
                    sh8 bf = *reinterpret_cast<const sh8*>(wbW + ((size_t)(t * 4 + kc)) * 1024);
                    sh8 a0 = *reinterpret_cast<const sh8*>(ap + kc * 16);
                    sh8 a1 = *reinterpret_cast<const sh8*>(ap + PW64 + kc * 16);
                    acc0 = mfma_bf16(a0, bf, acc0);
                    acc1 = mfma_bf16(a1, bf, acc1);
                }
            }
        }
    }

    const float bq = addmode ? 0.f : bsum[b * 64 + n * 32 + l31];
#pragma unroll
    for (int i = 0; i < 2; ++i) {
        f32x16 a = i ? acc1 : acc0;
        const int h = h0 + i;
#pragma unroll
        for (int r = 0; r < 16; ++r) {
            int px = (r & 3) + 8 * (r >> 2) + 4 * lh;
            lt[wid][px][l31] = a[r] + bq;
        }
        const int q = lh, co = l31;
        const size_t ob = ((size_t)(b * 64 + n * 32 + co)) * HWSZ + (size_t)h * WW + w0 + q * 16;
#pragma unroll
        for (int v = 0; v < 4; ++v) {
            float o0 = lt[wid][q * 16 + v * 4 + 0][co];
            float o1 = lt[wid][q * 16 + v * 4 + 1][co];
            float o2 = lt[wid][q * 16 + v * 4 + 2][co];
            float o3 = lt[wid][q * 16 + v * 4 + 3][co];
            float4* dst = reinterpret_cast<float4*>(outF + ob + v * 4);
            if (addmode) {
                float4 pv = *dst;
                o0 += pv.x; o1 += pv.y; o2 += pv.z; o3 += pv.w;
            }
            float4 o; o.x = o0; o.y = o1; o.z = o2; o.w = o3;
            *dst = o;
        }
    }
}

extern "C" void kernel_launch(void* const* d_in, const int* in_sizes, int n_in,
                              void* d_out, int out_size, void* d_ws, size_t ws_size,
                              hipStream_t stream) {
    const float* x  = (const float*)d_in[0];
    const float* rw = (const float*)d_in[1];
    const float* rb = (const float*)d_in[2];
    const float* eb = (const float*)d_in[3];
    const float* w1 = (const float*)d_in[4];
    const float* b1 = (const float*)d_in[5];
    const float* w2 = (const float*)d_in[6];
    const float* b2 = (const float*)d_in[7];
    float* out = (float*)d_out;

    char* ws = (char*)d_ws;
    float*    pooled = (float*)(ws + 0);
    int*      topi   = (int*)(ws + 2048);
    float*    topw   = (float*)(ws + 2112);
    float*    bsum   = (float*)(ws + 2176);
    ushort_t* wb1f   = (ushort_t*)(ws + 4352);
    ushort_t* wb2f   = (ushort_t*)(ws + 446720);
    ushort_t* xp     = (ushort_t*)(ws + 1626368);
    ushort_t* hp     = (ushort_t*)(ws + 18931968);

    const bool two = ws_size >= 53543168ull;  // hp holds both slots?

    hipLaunchKernelGGL(pool_kernel, dim3(512), dim3(256), 0, stream, x, pooled);
    hipLaunchKernelGGL(router_kernel, dim3(1), dim3(64), 0, stream,
                       pooled, rw, rb, eb, b2, topi, topw, bsum, out);
    hipLaunchKernelGGL(convx_kernel, dim3(1024), dim3(256), 0, stream, x, xp);
    hipLaunchKernelGGL(convw1_kernel, dim3(54), dim3(256), 0, stream, w1, wb1f);
    hipLaunchKernelGGL(convw2_kernel, dim3(144), dim3(256), 0, stream, w2, topi, topw, wb2f);
    hipLaunchKernelGGL(halo_kernel, dim3(8), dim3(256), 0, stream, xp);
    hipLaunchKernelGGL(halo_kernel, dim3(two ? 16 : 8), dim3(256), 0, stream, hp);

    if (two) {
        hipLaunchKernelGGL(conv1_mfma, dim3(64, 1, 16), dim3(256), 0, stream,
                           xp, wb1f, b1, topi, hp, 2, 0);
        hipLaunchKernelGGL(conv2_mfma, dim3(128, 1, 8), dim3(256), 0, stream,
                           hp, wb2f, bsum, out, 0, 1, 0);
    } else {
        hipLaunchKernelGGL(conv1_mfma, dim3(64, 1, 8), dim3(256), 0, stream,
                           xp, wb1f, b1, topi, hp, 1, 0);
        hipLaunchKernelGGL(conv2_mfma, dim3(128, 1, 8), dim3(256), 0, stream,
                           hp, wb2f, bsum, out, 0, 0, 0);
        hipLaunchKernelGGL(conv1_mfma, dim3(64, 1, 8), dim3(256), 0, stream,
                           xp, wb1f, b1, topi, hp, 1, 1);
        hipLaunchKernelGGL(conv2_mfma, dim3(128, 1, 8), dim3(256), 0, stream,
                           hp, wb2f, bsum, out, 1, 1, 1);
    }
}